// Round 2
// baseline (181.794 us; speedup 1.0000x reference)
//
#include <hip/hip_runtime.h>

#define NN 3072
#define F 256
#define NH 8
#define HD 32
#define ALPHA 0.2f
#define LN_EPS 1e-5f
#define CH 384  // edge chunk for weight buffer

// ---------------- Kernel A: h = x @ W^T  (N x F) ----------------
__global__ __launch_bounds__(256) void gemm_xwT(const float* __restrict__ x,
                                                const float* __restrict__ W,
                                                float* __restrict__ h) {
  __shared__ float xs[16][F];
  const int t = threadIdx.x;
  const int bi = blockIdx.x;
  for (int r = 0; r < 16; ++r) xs[r][t] = x[(size_t)(bi * 16 + r) * F + t];
  __syncthreads();
  float acc[16];
#pragma unroll
  for (int r = 0; r < 16; ++r) acc[r] = 0.f;
  const float* wrow = W + (size_t)t * F;
  for (int k = 0; k < F; k += 4) {
    const float4 w4 = *(const float4*)(wrow + k);
#pragma unroll
    for (int r = 0; r < 16; ++r) {
      const float4 xv = *(const float4*)(&xs[r][k]);
      acc[r] += w4.x * xv.x + w4.y * xv.y + w4.z * xv.z + w4.w * xv.w;
    }
  }
  for (int r = 0; r < 16; ++r) h[(size_t)(bi * 16 + r) * F + t] = acc[r];
}

// ---------------- Kernel B: a_src/a_dst = einsum(nhd,hd->nh) ----------------
__global__ __launch_bounds__(256) void head_proj(const float* __restrict__ h,
                                                 const float* __restrict__ asrc_w,
                                                 const float* __restrict__ adst_w,
                                                 float* __restrict__ a_src,
                                                 float* __restrict__ a_dst) {
  const int idx = blockIdx.x * 256 + threadIdx.x;  // i*8 + head
  const int i = idx >> 3, hh = idx & 7;
  const float* hp = h + (size_t)i * F + hh * HD;
  const float* ws_ = asrc_w + hh * HD;
  const float* wd_ = adst_w + hh * HD;
  float s1 = 0.f, s2 = 0.f;
#pragma unroll
  for (int d = 0; d < HD; ++d) {
    const float v = hp[d];
    s1 += v * ws_[d];
    s2 += v * wd_[d];
  }
  a_src[idx] = s1;
  a_dst[idx] = s2;
}

// ---------------- Kernel C: sparse masked multi-head attention ----------------
// One block per node i. Compact nonzero adjacency entries (order-preserving),
// compute per-(edge,head) softmax weights ONCE into LDS (chunked), then
// accumulate feature gathers with a near-pure-memory inner loop.
__global__ __launch_bounds__(256) void gat_attn(const float* __restrict__ adj,
                                                const float* __restrict__ hfeat,
                                                const float* __restrict__ a_src,
                                                const float* __restrict__ a_dst,
                                                const float* __restrict__ edge_W,
                                                const float* __restrict__ edge_b,
                                                float* __restrict__ h_out) {
  __shared__ unsigned short eidx[NN];   // 6144 B
  __shared__ float evalv[NN];           // 12288 B
  __shared__ float wbuf[CH * NH];       // 12288 B
  __shared__ int psum[256];             // 1024 B (reused as float sred)
  __shared__ float wmax[4][NH];         // 128 B
  __shared__ float mfin[NH];            // 32 B
  const int t = threadIdx.x;
  const int i = blockIdx.x;
  const float* arow = adj + (size_t)i * NN;

  // ---- compaction: each thread owns 12 contiguous adjacency entries ----
  const float4 r0 = *(const float4*)(arow + t * 12);
  const float4 r1 = *(const float4*)(arow + t * 12 + 4);
  const float4 r2 = *(const float4*)(arow + t * 12 + 8);
  const float v[12] = {r0.x, r0.y, r0.z, r0.w, r1.x, r1.y, r1.z, r1.w,
                       r2.x, r2.y, r2.z, r2.w};
  int c = 0;
#pragma unroll
  for (int q = 0; q < 12; ++q) c += (v[q] > 0.f) ? 1 : 0;
  psum[t] = c;
  __syncthreads();
  for (int off = 1; off < 256; off <<= 1) {
    const int add = (t >= off) ? psum[t - off] : 0;
    __syncthreads();
    psum[t] += add;
    __syncthreads();
  }
  int wofs = psum[t] - c;  // exclusive prefix
  const int cnt = psum[255];
#pragma unroll
  for (int q = 0; q < 12; ++q) {
    if (v[q] > 0.f) {
      eidx[wofs] = (unsigned short)(t * 12 + q);
      evalv[wofs] = v[q];
      ++wofs;
    }
  }
  __syncthreads();

  // ---- phase 1: per-head max ----
  float base[NH], ew[NH], mx[NH];
#pragma unroll
  for (int hh = 0; hh < NH; ++hh) {
    base[hh] = a_src[i * NH + hh] + edge_b[hh];
    ew[hh] = edge_W[hh];
    mx[hh] = -1e30f;
  }
  for (int e = t; e < cnt; e += 256) {
    const int j = eidx[e];
    const float av = evalv[e];
    const float4 ad0 = *(const float4*)(a_dst + j * NH);
    const float4 ad1 = *(const float4*)(a_dst + j * NH + 4);
    const float adv[8] = {ad0.x, ad0.y, ad0.z, ad0.w, ad1.x, ad1.y, ad1.z, ad1.w};
#pragma unroll
    for (int hh = 0; hh < NH; ++hh) {
      float l = base[hh] + adv[hh] + av * ew[hh];
      l = (l >= 0.f) ? l : ALPHA * l;
      mx[hh] = fmaxf(mx[hh], l);
    }
  }
#pragma unroll
  for (int off = 1; off < 64; off <<= 1) {
#pragma unroll
    for (int hh = 0; hh < NH; ++hh) mx[hh] = fmaxf(mx[hh], __shfl_xor(mx[hh], off));
  }
  if ((t & 63) == 0) {
#pragma unroll
    for (int hh = 0; hh < NH; ++hh) wmax[t >> 6][hh] = mx[hh];
  }
  __syncthreads();
  if (t < NH) {
    mfin[t] = fmaxf(fmaxf(wmax[0][t], wmax[1][t]),
                    fmaxf(wmax[2][t], wmax[3][t]));
  }
  __syncthreads();

  // ---- chunked: weight precompute (once per edge,head) + feature accumulate ----
  const int hw = t & 7;          // head this thread computes weights for
  const float baseW = base[hw];
  const float ewW = ew[hw];
  const float mW = mfin[hw];
  const int hh2 = t >> 5;        // head this thread accumulates features for
  float sw = 0.f;                // partial denominator (head hw)
  float acc0 = 0.f, acc1 = 0.f;
  for (int e0 = 0; e0 < cnt; e0 += CH) {
    const int ne = min(CH, cnt - e0);
    // weights for this chunk: ne*8 values over 256 threads
    for (int idx = t; idx < ne * NH; idx += 256) {
      const int e = e0 + (idx >> 3);
      const int j = eidx[e];
      float l = baseW + a_dst[j * NH + hw] + evalv[e] * ewW;
      l = (l >= 0.f) ? l : ALPHA * l;
      const float w = __expf(l - mW);
      wbuf[idx] = w;
      sw += w;
    }
    __syncthreads();
    // feature accumulate over this chunk (2 accumulators for dep-chain)
    const float* wb = wbuf + hh2 - (size_t)e0 * NH;
    int e = e0;
    for (; e + 1 < e0 + ne; e += 2) {
      const int ja = eidx[e], jb = eidx[e + 1];
      acc0 += wb[(size_t)e * NH] * hfeat[(size_t)ja * F + t];
      acc1 += wb[(size_t)(e + 1) * NH] * hfeat[(size_t)jb * F + t];
    }
    if (e < e0 + ne) {
      const int ja = eidx[e];
      acc0 += wb[(size_t)e * NH] * hfeat[(size_t)ja * F + t];
    }
    __syncthreads();
  }

  // ---- denominator reduction: threads with same (t&7) hold partials ----
  float* sred = (float*)psum;
  sred[t] = sw;
  __syncthreads();
  for (int off = 128; off >= NH; off >>= 1) {
    if (t < off) sred[t] += sred[t + off];
    __syncthreads();
  }
  const float s = sred[hh2];
  h_out[(size_t)i * F + t] = (acc0 + acc1) / s;
}

// ---------------- Kernel D: y = h_out @ fuse_W^T + b, LayerNorm, ReLU ----------------
__global__ __launch_bounds__(256) void fuse_ln(const float* __restrict__ hin,
                                               const float* __restrict__ fW,
                                               const float* __restrict__ fb,
                                               const float* __restrict__ ln_g,
                                               const float* __restrict__ ln_b,
                                               float* __restrict__ out) {
  __shared__ float xs[16][F];
  __shared__ float ys[16][F];
  __shared__ float mu_s[16], rs_s[16];
  const int t = threadIdx.x;
  const int bi = blockIdx.x;
  for (int r = 0; r < 16; ++r) xs[r][t] = hin[(size_t)(bi * 16 + r) * F + t];
  __syncthreads();
  float acc[16];
#pragma unroll
  for (int r = 0; r < 16; ++r) acc[r] = 0.f;
  const float* wrow = fW + (size_t)t * F;
  for (int k = 0; k < F; k += 4) {
    const float4 w4 = *(const float4*)(wrow + k);
#pragma unroll
    for (int r = 0; r < 16; ++r) {
      const float4 xv = *(const float4*)(&xs[r][k]);
      acc[r] += w4.x * xv.x + w4.y * xv.y + w4.z * xv.z + w4.w * xv.w;
    }
  }
  const float fbt = fb[t];
  for (int r = 0; r < 16; ++r) ys[r][t] = acc[r] + fbt;
  __syncthreads();
  {
    const int r = t >> 4, c0 = t & 15;
    float sm = 0.f, sq = 0.f;
    for (int cc = c0; cc < F; cc += 16) {
      const float vv = ys[r][cc];
      sm += vv;
      sq += vv * vv;
    }
#pragma unroll
    for (int off = 1; off < 16; off <<= 1) {
      sm += __shfl_xor(sm, off);
      sq += __shfl_xor(sq, off);
    }
    if (c0 == 0) {
      const float mu = sm * (1.f / F);
      const float var = sq * (1.f / F) - mu * mu;
      mu_s[r] = mu;
      rs_s[r] = rsqrtf(var + LN_EPS);
    }
  }
  __syncthreads();
  const float g = ln_g[t], b = ln_b[t];
  for (int r = 0; r < 16; ++r) {
    const float vv = (ys[r][t] - mu_s[r]) * rs_s[r] * g + b;
    out[(size_t)(bi * 16 + r) * F + t] = fmaxf(vv, 0.f);
  }
}

extern "C" void kernel_launch(void* const* d_in, const int* in_sizes, int n_in,
                              void* d_out, int out_size, void* d_ws, size_t ws_size,
                              hipStream_t stream) {
  const float* x = (const float*)d_in[0];
  const float* adj = (const float*)d_in[1];
  const float* W = (const float*)d_in[2];
  const float* attn_src = (const float*)d_in[3];
  const float* attn_dst = (const float*)d_in[4];
  const float* edge_W = (const float*)d_in[5];
  const float* edge_b = (const float*)d_in[6];
  const float* fuse_W = (const float*)d_in[7];
  const float* fuse_b = (const float*)d_in[8];
  const float* ln_g = (const float*)d_in[9];
  const float* ln_b = (const float*)d_in[10];
  float* out = (float*)d_out;

  float* ws = (float*)d_ws;
  float* h = ws;                              // N*F
  float* a_src = h + (size_t)NN * F;          // N*8
  float* a_dst = a_src + (size_t)NN * NH;     // N*8
  float* h_out = a_dst + (size_t)NN * NH;     // N*F

  gemm_xwT<<<NN / 16, 256, 0, stream>>>(x, W, h);
  head_proj<<<NN * NH / 256, 256, 0, stream>>>(h, attn_src, attn_dst, a_src, a_dst);
  gat_attn<<<NN, 256, 0, stream>>>(adj, h, a_src, a_dst, edge_W, edge_b, h_out);
  fuse_ln<<<NN / 16, 256, 0, stream>>>(h_out, fuse_W, fuse_b, ln_g, ln_b, out);
}

// Round 3
// 120.954 us; speedup vs baseline: 1.5030x; 1.5030x over previous
//
#include <hip/hip_runtime.h>

#define NN 3072
#define F 256
#define NH 8
#define HD 32
#define ALPHA 0.2f
#define LN_EPS 1e-5f
#define CH 384  // edge chunk for weight buffer
#define BW 16   // gather batch width (outstanding loads per thread)

// ---------------- Kernel A: h = x @ W^T  (N x F) ----------------
__global__ __launch_bounds__(256) void gemm_xwT(const float* __restrict__ x,
                                                const float* __restrict__ W,
                                                float* __restrict__ h) {
  __shared__ float xs[16][F];
  const int t = threadIdx.x;
  const int bi = blockIdx.x;
  for (int r = 0; r < 16; ++r) xs[r][t] = x[(size_t)(bi * 16 + r) * F + t];
  __syncthreads();
  float acc[16];
#pragma unroll
  for (int r = 0; r < 16; ++r) acc[r] = 0.f;
  const float* wrow = W + (size_t)t * F;
  for (int k = 0; k < F; k += 4) {
    const float4 w4 = *(const float4*)(wrow + k);
#pragma unroll
    for (int r = 0; r < 16; ++r) {
      const float4 xv = *(const float4*)(&xs[r][k]);
      acc[r] += w4.x * xv.x + w4.y * xv.y + w4.z * xv.z + w4.w * xv.w;
    }
  }
  for (int r = 0; r < 16; ++r) h[(size_t)(bi * 16 + r) * F + t] = acc[r];
}

// ---------------- Kernel B: a_src/a_dst = einsum(nhd,hd->nh) ----------------
__global__ __launch_bounds__(256) void head_proj(const float* __restrict__ h,
                                                 const float* __restrict__ asrc_w,
                                                 const float* __restrict__ adst_w,
                                                 float* __restrict__ a_src,
                                                 float* __restrict__ a_dst) {
  const int idx = blockIdx.x * 256 + threadIdx.x;  // i*8 + head
  const int i = idx >> 3, hh = idx & 7;
  const float* hp = h + (size_t)i * F + hh * HD;
  const float* ws_ = asrc_w + hh * HD;
  const float* wd_ = adst_w + hh * HD;
  float s1 = 0.f, s2 = 0.f;
#pragma unroll
  for (int d = 0; d < HD; ++d) {
    const float v = hp[d];
    s1 += v * ws_[d];
    s2 += v * wd_[d];
  }
  a_src[idx] = s1;
  a_dst[idx] = s2;
}

// ---------------- Kernel C: sparse masked multi-head attention ----------------
// One block per node i. Compact nonzero adjacency entries (order-preserving),
// per-(edge,head) softmax weights computed once into LDS (transposed layout),
// then 16-wide batched feature gathers for memory-level parallelism.
__global__ __launch_bounds__(256) void gat_attn(const float* __restrict__ adj,
                                                const float* __restrict__ hfeat,
                                                const float* __restrict__ a_src,
                                                const float* __restrict__ a_dst,
                                                const float* __restrict__ edge_W,
                                                const float* __restrict__ edge_b,
                                                float* __restrict__ h_out) {
  __shared__ unsigned short eidx[NN + BW];  // 6176 B (padded)
  __shared__ float evalv[NN];               // 12288 B
  __shared__ float wbuf[NH][CH + 1];        // 12320 B, transposed + pad
  __shared__ int psum[256];                 // 1024 B (reused as float sred)
  __shared__ float wmax[4][NH];
  __shared__ float mfin[NH];
  const int t = threadIdx.x;
  const int i = blockIdx.x;
  const float* arow = adj + (size_t)i * NN;

  // ---- compaction: each thread owns 12 contiguous adjacency entries ----
  const float4 r0 = *(const float4*)(arow + t * 12);
  const float4 r1 = *(const float4*)(arow + t * 12 + 4);
  const float4 r2 = *(const float4*)(arow + t * 12 + 8);
  const float v[12] = {r0.x, r0.y, r0.z, r0.w, r1.x, r1.y, r1.z, r1.w,
                       r2.x, r2.y, r2.z, r2.w};
  int c = 0;
#pragma unroll
  for (int q = 0; q < 12; ++q) c += (v[q] > 0.f) ? 1 : 0;
  psum[t] = c;
  __syncthreads();
  for (int off = 1; off < 256; off <<= 1) {
    const int add = (t >= off) ? psum[t - off] : 0;
    __syncthreads();
    psum[t] += add;
    __syncthreads();
  }
  int wofs = psum[t] - c;  // exclusive prefix
  const int cnt = psum[255];
#pragma unroll
  for (int q = 0; q < 12; ++q) {
    if (v[q] > 0.f) {
      eidx[wofs] = (unsigned short)(t * 12 + q);
      evalv[wofs] = v[q];
      ++wofs;
    }
  }
  if (t < BW) eidx[cnt + t] = 0;  // safe pad indices (weights will be 0)
  __syncthreads();

  // ---- phase 1: per-head max ----
  float base[NH], ew[NH], mx[NH];
#pragma unroll
  for (int hh = 0; hh < NH; ++hh) {
    base[hh] = a_src[i * NH + hh] + edge_b[hh];
    ew[hh] = edge_W[hh];
    mx[hh] = -1e30f;
  }
  for (int e = t; e < cnt; e += 256) {
    const int j = eidx[e];
    const float av = evalv[e];
    const float4 ad0 = *(const float4*)(a_dst + j * NH);
    const float4 ad1 = *(const float4*)(a_dst + j * NH + 4);
    const float adv[8] = {ad0.x, ad0.y, ad0.z, ad0.w, ad1.x, ad1.y, ad1.z, ad1.w};
#pragma unroll
    for (int hh = 0; hh < NH; ++hh) {
      float l = base[hh] + adv[hh] + av * ew[hh];
      l = (l >= 0.f) ? l : ALPHA * l;
      mx[hh] = fmaxf(mx[hh], l);
    }
  }
#pragma unroll
  for (int off = 1; off < 64; off <<= 1) {
#pragma unroll
    for (int hh = 0; hh < NH; ++hh) mx[hh] = fmaxf(mx[hh], __shfl_xor(mx[hh], off));
  }
  if ((t & 63) == 0) {
#pragma unroll
    for (int hh = 0; hh < NH; ++hh) wmax[t >> 6][hh] = mx[hh];
  }
  __syncthreads();
  if (t < NH) {
    mfin[t] = fmaxf(fmaxf(wmax[0][t], wmax[1][t]),
                    fmaxf(wmax[2][t], wmax[3][t]));
  }
  __syncthreads();

  // ---- chunked: weight precompute + batched feature accumulate ----
  const int hw = t & 7;          // head this thread computes weights for
  const float baseW = base[hw];
  const float ewW = ew[hw];
  const float mW = mfin[hw];
  const int hh2 = t >> 5;        // head this thread accumulates features for
  float sw = 0.f;                // partial denominator (head hw)
  float acc = 0.f;
  for (int e0 = 0; e0 < cnt; e0 += CH) {
    const int ne = min(CH, cnt - e0);
    const int nep = (ne + BW - 1) & ~(BW - 1);  // padded edge count
    // weights for this chunk: nep*8 values over 256 threads; pads get w=0
    for (int idx = t; idx < nep * NH; idx += 256) {
      const int el = idx >> 3;  // local edge (idx&7 == t&7 == hw since 8|256)
      float w = 0.f;
      if (el < ne) {
        const int e = e0 + el;
        const int j = eidx[e];
        float l = baseW + a_dst[j * NH + hw] + evalv[e] * ewW;
        l = (l >= 0.f) ? l : ALPHA * l;
        w = __expf(l - mW);
      }
      wbuf[hw][el] = w;
      sw += w;
    }
    __syncthreads();
    // batched accumulate: BW outstanding gathers per thread
    const float* wb = wbuf[hh2];
    const unsigned short* ei = eidx + e0;
    for (int el = 0; el < nep; el += BW) {
      int j[BW];
      float w[BW], f[BW];
#pragma unroll
      for (int q = 0; q < BW; ++q) {
        j[q] = ei[el + q];
        w[q] = wb[el + q];
      }
#pragma unroll
      for (int q = 0; q < BW; ++q) f[q] = hfeat[(size_t)j[q] * F + t];
#pragma unroll
      for (int q = 0; q < BW; ++q) acc += w[q] * f[q];
    }
    __syncthreads();
  }

  // ---- denominator reduction: threads with same (t&7) hold partials ----
  float* sred = (float*)psum;
  sred[t] = sw;
  __syncthreads();
  for (int off = 128; off >= NH; off >>= 1) {
    if (t < off) sred[t] += sred[t + off];
    __syncthreads();
  }
  const float s = sred[hh2];
  h_out[(size_t)i * F + t] = acc / s;
}

// ---------------- Kernel D: y = h_out @ fuse_W^T + b, LayerNorm, ReLU ----------------
__global__ __launch_bounds__(256) void fuse_ln(const float* __restrict__ hin,
                                               const float* __restrict__ fW,
                                               const float* __restrict__ fb,
                                               const float* __restrict__ ln_g,
                                               const float* __restrict__ ln_b,
                                               float* __restrict__ out) {
  __shared__ float xs[16][F];
  __shared__ float ys[16][F];
  __shared__ float mu_s[16], rs_s[16];
  const int t = threadIdx.x;
  const int bi = blockIdx.x;
  for (int r = 0; r < 16; ++r) xs[r][t] = hin[(size_t)(bi * 16 + r) * F + t];
  __syncthreads();
  float acc[16];
#pragma unroll
  for (int r = 0; r < 16; ++r) acc[r] = 0.f;
  const float* wrow = fW + (size_t)t * F;
  for (int k = 0; k < F; k += 4) {
    const float4 w4 = *(const float4*)(wrow + k);
#pragma unroll
    for (int r = 0; r < 16; ++r) {
      const float4 xv = *(const float4*)(&xs[r][k]);
      acc[r] += w4.x * xv.x + w4.y * xv.y + w4.z * xv.z + w4.w * xv.w;
    }
  }
  const float fbt = fb[t];
  for (int r = 0; r < 16; ++r) ys[r][t] = acc[r] + fbt;
  __syncthreads();
  {
    const int r = t >> 4, c0 = t & 15;
    float sm = 0.f, sq = 0.f;
    for (int cc = c0; cc < F; cc += 16) {
      const float vv = ys[r][cc];
      sm += vv;
      sq += vv * vv;
    }
#pragma unroll
    for (int off = 1; off < 16; off <<= 1) {
      sm += __shfl_xor(sm, off);
      sq += __shfl_xor(sq, off);
    }
    if (c0 == 0) {
      const float mu = sm * (1.f / F);
      const float var = sq * (1.f / F) - mu * mu;
      mu_s[r] = mu;
      rs_s[r] = rsqrtf(var + LN_EPS);
    }
  }
  __syncthreads();
  const float g = ln_g[t], b = ln_b[t];
  for (int r = 0; r < 16; ++r) {
    const float vv = (ys[r][t] - mu_s[r]) * rs_s[r] * g + b;
    out[(size_t)(bi * 16 + r) * F + t] = fmaxf(vv, 0.f);
  }
}

extern "C" void kernel_launch(void* const* d_in, const int* in_sizes, int n_in,
                              void* d_out, int out_size, void* d_ws, size_t ws_size,
                              hipStream_t stream) {
  const float* x = (const float*)d_in[0];
  const float* adj = (const float*)d_in[1];
  const float* W = (const float*)d_in[2];
  const float* attn_src = (const float*)d_in[3];
  const float* attn_dst = (const float*)d_in[4];
  const float* edge_W = (const float*)d_in[5];
  const float* edge_b = (const float*)d_in[6];
  const float* fuse_W = (const float*)d_in[7];
  const float* fuse_b = (const float*)d_in[8];
  const float* ln_g = (const float*)d_in[9];
  const float* ln_b = (const float*)d_in[10];
  float* out = (float*)d_out;

  float* ws = (float*)d_ws;
  float* h = ws;                              // N*F
  float* a_src = h + (size_t)NN * F;          // N*8
  float* a_dst = a_src + (size_t)NN * NH;     // N*8
  float* h_out = a_dst + (size_t)NN * NH;     // N*F

  gemm_xwT<<<NN / 16, 256, 0, stream>>>(x, W, h);
  head_proj<<<NN * NH / 256, 256, 0, stream>>>(h, attn_src, attn_dst, a_src, a_dst);
  gat_attn<<<NN, 256, 0, stream>>>(adj, h, a_src, a_dst, edge_W, edge_b, h_out);
  fuse_ln<<<NN / 16, 256, 0, stream>>>(h_out, fuse_W, fuse_b, ln_g, ln_b, out);
}

// Round 5
// 104.103 us; speedup vs baseline: 1.7463x; 1.1619x over previous
//
#include <hip/hip_runtime.h>

#define NN 3072
#define F 256
#define NH 8
#define HD 32
#define ALPHA 0.2f
#define LN_EPS 1e-5f
#define CH 384  // edge chunk for weight buffer (multiple of 32)

typedef float floatx4 __attribute__((ext_vector_type(4)));

// ---------------- Kernel A: h = x @ W^T  (N x F), 8 rows/block ----------------
__global__ __launch_bounds__(256) void gemm_xwT(const float* __restrict__ x,
                                                const float* __restrict__ W,
                                                float* __restrict__ h) {
  __shared__ float xs[8][F];
  const int t = threadIdx.x;
  const int bi = blockIdx.x;
  for (int r = 0; r < 8; ++r) xs[r][t] = x[(size_t)(bi * 8 + r) * F + t];
  __syncthreads();
  float acc[8];
#pragma unroll
  for (int r = 0; r < 8; ++r) acc[r] = 0.f;
  const float* wrow = W + (size_t)t * F;
  for (int k = 0; k < F; k += 4) {
    const float4 w4 = *(const float4*)(wrow + k);
#pragma unroll
    for (int r = 0; r < 8; ++r) {
      const float4 xv = *(const float4*)(&xs[r][k]);
      acc[r] += w4.x * xv.x + w4.y * xv.y + w4.z * xv.z + w4.w * xv.w;
    }
  }
  for (int r = 0; r < 8; ++r) h[(size_t)(bi * 8 + r) * F + t] = acc[r];
}

// ---------------- Kernel B: a_src/a_dst = einsum(nhd,hd->nh) ----------------
__global__ __launch_bounds__(256) void head_proj(const float* __restrict__ h,
                                                 const float* __restrict__ asrc_w,
                                                 const float* __restrict__ adst_w,
                                                 float* __restrict__ a_src,
                                                 float* __restrict__ a_dst) {
  const int idx = blockIdx.x * 256 + threadIdx.x;  // i*8 + head
  const int i = idx >> 3, hh = idx & 7;
  const float* hp = h + (size_t)i * F + hh * HD;
  const float* ws_ = asrc_w + hh * HD;
  const float* wd_ = adst_w + hh * HD;
  float s1 = 0.f, s2 = 0.f;
#pragma unroll
  for (int d = 0; d < HD; ++d) {
    const float v = hp[d];
    s1 += v * ws_[d];
    s2 += v * wd_[d];
  }
  a_src[idx] = s1;
  a_dst[idx] = s2;
}

// ---------------- Kernel C: sparse masked multi-head attention ----------------
// One block per node i. Compaction, per-(edge,head) weights once into LDS
// (conflict-free [CH][NH] layout), then float4 gathers: one wave reads a full
// 1KB feature row per edge (16B/lane), 8 rows in flight per wave.
__global__ __launch_bounds__(256) void gat_attn(const float* __restrict__ adj,
                                                const float* __restrict__ hfeat,
                                                const float* __restrict__ a_src,
                                                const float* __restrict__ a_dst,
                                                const float* __restrict__ edge_W,
                                                const float* __restrict__ edge_b,
                                                float* __restrict__ h_out) {
  __shared__ unsigned short eidx[NN + 32];  // padded
  __shared__ float evalv[NN];
  __shared__ float wbuf[CH][NH];            // 12 KB, conflict-free layout
  __shared__ int psum[256];                 // reused as float sred
  __shared__ float wmax[4][NH];
  __shared__ float mfin[NH];
  const int t = threadIdx.x;
  const int i = blockIdx.x;
  const float* arow = adj + (size_t)i * NN;

  // ---- compaction: each thread owns 12 contiguous adjacency entries ----
  const floatx4 r0 = __builtin_nontemporal_load((const floatx4*)(arow + t * 12));
  const floatx4 r1 = __builtin_nontemporal_load((const floatx4*)(arow + t * 12 + 4));
  const floatx4 r2 = __builtin_nontemporal_load((const floatx4*)(arow + t * 12 + 8));
  const float v[12] = {r0.x, r0.y, r0.z, r0.w, r1.x, r1.y, r1.z, r1.w,
                       r2.x, r2.y, r2.z, r2.w};
  int c = 0;
#pragma unroll
  for (int q = 0; q < 12; ++q) c += (v[q] > 0.f) ? 1 : 0;
  psum[t] = c;
  __syncthreads();
  for (int off = 1; off < 256; off <<= 1) {
    const int add = (t >= off) ? psum[t - off] : 0;
    __syncthreads();
    psum[t] += add;
    __syncthreads();
  }
  int wofs = psum[t] - c;  // exclusive prefix
  const int cnt = psum[255];
#pragma unroll
  for (int q = 0; q < 12; ++q) {
    if (v[q] > 0.f) {
      eidx[wofs] = (unsigned short)(t * 12 + q);
      evalv[wofs] = v[q];
      ++wofs;
    }
  }
  if (t < 32) eidx[cnt + t] = 0;  // safe pad (their weights are 0)
  __syncthreads();

  // ---- phase 1: per-head max ----
  float base[NH], ew[NH], mx[NH];
#pragma unroll
  for (int hh = 0; hh < NH; ++hh) {
    base[hh] = a_src[i * NH + hh] + edge_b[hh];
    ew[hh] = edge_W[hh];
    mx[hh] = -1e30f;
  }
  for (int e = t; e < cnt; e += 256) {
    const int j = eidx[e];
    const float av = evalv[e];
    const float4 ad0 = *(const float4*)(a_dst + j * NH);
    const float4 ad1 = *(const float4*)(a_dst + j * NH + 4);
    const float adv[8] = {ad0.x, ad0.y, ad0.z, ad0.w, ad1.x, ad1.y, ad1.z, ad1.w};
#pragma unroll
    for (int hh = 0; hh < NH; ++hh) {
      float l = base[hh] + adv[hh] + av * ew[hh];
      l = (l >= 0.f) ? l : ALPHA * l;
      mx[hh] = fmaxf(mx[hh], l);
    }
  }
#pragma unroll
  for (int off = 1; off < 64; off <<= 1) {
#pragma unroll
    for (int hh = 0; hh < NH; ++hh) mx[hh] = fmaxf(mx[hh], __shfl_xor(mx[hh], off));
  }
  if ((t & 63) == 0) {
#pragma unroll
    for (int hh = 0; hh < NH; ++hh) wmax[t >> 6][hh] = mx[hh];
  }
  __syncthreads();
  if (t < NH) {
    mfin[t] = fmaxf(fmaxf(wmax[0][t], wmax[1][t]),
                    fmaxf(wmax[2][t], wmax[3][t]));
  }
  __syncthreads();

  // ---- chunked: weight precompute + float4 wave-split gathers ----
  const int hw = t & 7;          // head this thread computes weights for
  const float baseW = base[hw];
  const float ewW = ew[hw];
  const float mW = mfin[hw];
  const int w = t >> 6;          // wave id
  const int l = t & 63;          // lane; owns features 4l..4l+3
  const int headF = l >> 3;      // head of this lane's float4
  float sw = 0.f;                // partial denominator (head hw)
  float4 acc4 = {0.f, 0.f, 0.f, 0.f};
  for (int e0 = 0; e0 < cnt; e0 += CH) {
    const int ne = min(CH, cnt - e0);
    const int nep = (ne + 31) & ~31;
    // weights: (el, hw) over 256 threads; conflict-free writes
    for (int idx = t; idx < ne * NH; idx += 256) {
      const int el = idx >> 3;  // idx&7 == hw since 8 | 256
      const int e = e0 + el;
      const int j = eidx[e];
      float lg = baseW + a_dst[j * NH + hw] + evalv[e] * ewW;
      lg = (lg >= 0.f) ? lg : ALPHA * lg;
      const float wv = __expf(lg - mW);
      wbuf[el][hw] = wv;
      sw += wv;
    }
    for (int el = ne + (t >> 3); el < nep; el += 32) wbuf[el][hw] = 0.f;  // pad
    __syncthreads();
    // gather: wave w handles edges el ≡ w (mod 4); 8 rows (8×16B/lane) in flight
    const int nb = nep >> 5;
    for (int b = 0; b < nb; ++b) {
      int j[8];
      float wv[8];
      float4 f[8];
#pragma unroll
      for (int q = 0; q < 8; ++q) {
        const int el = w + b * 32 + q * 4;
        j[q] = eidx[e0 + el];
        wv[q] = wbuf[el][headF];
      }
#pragma unroll
      for (int q = 0; q < 8; ++q)
        f[q] = *(const float4*)(hfeat + (size_t)j[q] * F + 4 * l);
#pragma unroll
      for (int q = 0; q < 8; ++q) {
        acc4.x += wv[q] * f[q].x;
        acc4.y += wv[q] * f[q].y;
        acc4.z += wv[q] * f[q].z;
        acc4.w += wv[q] * f[q].w;
      }
    }
    __syncthreads();
  }

  // ---- cross-wave reduction of float4 partials + denominator ----
  float* red = &wbuf[0][0];  // reuse 4KB of wbuf
  *(float4*)(red + w * F + 4 * l) = acc4;
  float* sred = (float*)psum;
  sred[t] = sw;
  __syncthreads();
  for (int off = 128; off >= NH; off >>= 1) {
    if (t < off) sred[t] += sred[t + off];
    __syncthreads();
  }
  const float s = sred[t >> 5];
  h_out[(size_t)i * F + t] =
      (red[t] + red[F + t] + red[2 * F + t] + red[3 * F + t]) / s;
}

// ---------------- Kernel D: y = h_out @ fuse_W^T + b, LayerNorm, ReLU ----------------
__global__ __launch_bounds__(256) void fuse_ln(const float* __restrict__ hin,
                                               const float* __restrict__ fW,
                                               const float* __restrict__ fb,
                                               const float* __restrict__ ln_g,
                                               const float* __restrict__ ln_b,
                                               float* __restrict__ out) {
  __shared__ float xs[8][F];
  __shared__ float ys[8][F];
  __shared__ float mu_s[8], rs_s[8];
  const int t = threadIdx.x;
  const int bi = blockIdx.x;
  for (int r = 0; r < 8; ++r) xs[r][t] = hin[(size_t)(bi * 8 + r) * F + t];
  __syncthreads();
  float acc[8];
#pragma unroll
  for (int r = 0; r < 8; ++r) acc[r] = 0.f;
  const float* wrow = fW + (size_t)t * F;
  for (int k = 0; k < F; k += 4) {
    const float4 w4 = *(const float4*)(wrow + k);
#pragma unroll
    for (int r = 0; r < 8; ++r) {
      const float4 xv = *(const float4*)(&xs[r][k]);
      acc[r] += w4.x * xv.x + w4.y * xv.y + w4.z * xv.z + w4.w * xv.w;
    }
  }
  const float fbt = fb[t];
  for (int r = 0; r < 8; ++r) ys[r][t] = acc[r] + fbt;
  __syncthreads();
  {
    const int r = t >> 5, c0 = t & 31;
    float sm = 0.f, sq = 0.f;
    for (int cc = c0; cc < F; cc += 32) {
      const float vv = ys[r][cc];
      sm += vv;
      sq += vv * vv;
    }
#pragma unroll
    for (int off = 1; off < 32; off <<= 1) {
      sm += __shfl_xor(sm, off);
      sq += __shfl_xor(sq, off);
    }
    if (c0 == 0) {
      const float mu = sm * (1.f / F);
      const float var = sq * (1.f / F) - mu * mu;
      mu_s[r] = mu;
      rs_s[r] = rsqrtf(var + LN_EPS);
    }
  }
  __syncthreads();
  const float g = ln_g[t], b = ln_b[t];
  for (int r = 0; r < 8; ++r) {
    const float vv = (ys[r][t] - mu_s[r]) * rs_s[r] * g + b;
    out[(size_t)(bi * 8 + r) * F + t] = fmaxf(vv, 0.f);
  }
}

extern "C" void kernel_launch(void* const* d_in, const int* in_sizes, int n_in,
                              void* d_out, int out_size, void* d_ws, size_t ws_size,
                              hipStream_t stream) {
  const float* x = (const float*)d_in[0];
  const float* adj = (const float*)d_in[1];
  const float* W = (const float*)d_in[2];
  const float* attn_src = (const float*)d_in[3];
  const float* attn_dst = (const float*)d_in[4];
  const float* edge_W = (const float*)d_in[5];
  const float* edge_b = (const float*)d_in[6];
  const float* fuse_W = (const float*)d_in[7];
  const float* fuse_b = (const float*)d_in[8];
  const float* ln_g = (const float*)d_in[9];
  const float* ln_b = (const float*)d_in[10];
  float* out = (float*)d_out;

  float* ws = (float*)d_ws;
  float* h = ws;                              // N*F
  float* a_src = h + (size_t)NN * F;          // N*8
  float* a_dst = a_src + (size_t)NN * NH;     // N*8
  float* h_out = a_dst + (size_t)NN * NH;     // N*F

  gemm_xwT<<<NN / 8, 256, 0, stream>>>(x, W, h);
  head_proj<<<NN * NH / 256, 256, 0, stream>>>(h, attn_src, attn_dst, a_src, a_dst);
  gat_attn<<<NN, 256, 0, stream>>>(adj, h, a_src, a_dst, edge_W, edge_b, h_out);
  fuse_ln<<<NN / 8, 256, 0, stream>>>(h_out, fuse_W, fuse_b, ln_g, ln_b, out);
}

// Round 6
// 99.114 us; speedup vs baseline: 1.8342x; 1.0503x over previous
//
#include <hip/hip_runtime.h>
#include <hip/hip_fp16.h>

#define NN 3072
#define F 256
#define NH 8
#define ALPHA 0.2f
#define LN_EPS 1e-5f
#define CH 384  // edge chunk (multiple of 64)
#define BW 16   // gathers in flight per thread

typedef float floatx4 __attribute__((ext_vector_type(4)));

// ---- Kernel A: h = x @ W^T (8 rows/block) + fused a_src/a_dst epilogue ----
__global__ __launch_bounds__(256) void gemm_xwT(const float* __restrict__ x,
                                                const float* __restrict__ W,
                                                const float* __restrict__ asrc_w,
                                                const float* __restrict__ adst_w,
                                                float* __restrict__ h,
                                                float* __restrict__ a_src,
                                                float* __restrict__ a_dst) {
  __shared__ float xs[8][F];
  const int t = threadIdx.x;
  const int bi = blockIdx.x;
  for (int r = 0; r < 8; ++r) xs[r][t] = x[(size_t)(bi * 8 + r) * F + t];
  __syncthreads();
  float acc[8];
#pragma unroll
  for (int r = 0; r < 8; ++r) acc[r] = 0.f;
  const float* wrow = W + (size_t)t * F;
  for (int k = 0; k < F; k += 4) {
    const float4 w4 = *(const float4*)(wrow + k);
#pragma unroll
    for (int r = 0; r < 8; ++r) {
      const float4 xv = *(const float4*)(&xs[r][k]);
      acc[r] += w4.x * xv.x + w4.y * xv.y + w4.z * xv.z + w4.w * xv.w;
    }
  }
  for (int r = 0; r < 8; ++r) h[(size_t)(bi * 8 + r) * F + t] = acc[r];
  // epilogue: a_src[i,hh] = sum_d h[i][hh*32+d]*asrc_w[hh*32+d]; col t weight = asrc_w[t]
  const float wsv = asrc_w[t];
  const float wdv = adst_w[t];
#pragma unroll
  for (int r = 0; r < 8; ++r) {
    float ps = acc[r] * wsv;
    float pd = acc[r] * wdv;
#pragma unroll
    for (int off = 1; off < 32; off <<= 1) {
      ps += __shfl_xor(ps, off);
      pd += __shfl_xor(pd, off);
    }
    if ((t & 31) == 0) {
      a_src[(size_t)(bi * 8 + r) * NH + (t >> 5)] = ps;
      a_dst[(size_t)(bi * 8 + r) * NH + (t >> 5)] = pd;
    }
  }
}

// ---- Kernel C: sparse masked multi-head attention, no-max softmax ----
__global__ __launch_bounds__(256, 4) void gat_attn(const float* __restrict__ adj,
                                                   const float* __restrict__ hfeat,
                                                   const float* __restrict__ a_src,
                                                   const float* __restrict__ a_dst,
                                                   const float* __restrict__ edge_W,
                                                   const float* __restrict__ edge_b,
                                                   float* __restrict__ h_out) {
  __shared__ unsigned packed[NN + 64];  // (j<<16)|f16(av), 12.5 KB
  __shared__ float wbuf[CH][NH];        // 12 KB, conflict-free
  __shared__ float sred[256];
  __shared__ int wsum[4];
  const int t = threadIdx.x;
  const int i = blockIdx.x;
  const int w = t >> 6, lane = t & 63;
  const float* arow = adj + (size_t)i * NN;

  // ---- compaction: 12 entries/thread, wave-scan (2 barriers) ----
  const floatx4 r0 = __builtin_nontemporal_load((const floatx4*)(arow + t * 12));
  const floatx4 r1 = __builtin_nontemporal_load((const floatx4*)(arow + t * 12 + 4));
  const floatx4 r2 = __builtin_nontemporal_load((const floatx4*)(arow + t * 12 + 8));
  const float v[12] = {r0.x, r0.y, r0.z, r0.w, r1.x, r1.y, r1.z, r1.w,
                       r2.x, r2.y, r2.z, r2.w};
  int c = 0;
#pragma unroll
  for (int q = 0; q < 12; ++q) c += (v[q] > 0.f) ? 1 : 0;
  int xinc = c;  // wave inclusive scan
#pragma unroll
  for (int off = 1; off < 64; off <<= 1) {
    const int y = __shfl_up(xinc, off);
    if (lane >= off) xinc += y;
  }
  if (lane == 63) wsum[w] = xinc;
  __syncthreads();
  int cnt = 0, wpre = 0;
#pragma unroll
  for (int ww = 0; ww < 4; ++ww) {
    const int s = wsum[ww];
    if (ww < w) wpre += s;
    cnt += s;
  }
  int wofs = wpre + xinc - c;  // exclusive prefix
#pragma unroll
  for (int q = 0; q < 12; ++q) {
    if (v[q] > 0.f) {
      const unsigned j = (unsigned)(t * 12 + q);
      packed[wofs++] = (j << 16) | (unsigned)__half_as_ushort(__float2half(v[q]));
    }
  }
  if (t < 64) packed[cnt + t] = 0;  // pad: j=0, av=0 (weights forced 0)
  __syncthreads();

  // ---- chunked: weights (no max; exp(l) directly) + 16-deep gathers ----
  const int hw = t & 7;
  const float baseW = a_src[i * NH + hw] + edge_b[hw];
  const float ewW = edge_W[hw];
  const int headF = lane >> 3;
  float sw = 0.f;
  float4 acc4 = {0.f, 0.f, 0.f, 0.f};
  for (int e0 = 0; e0 < cnt; e0 += CH) {
    const int ne = min(CH, cnt - e0);
    const int nep = (ne + 63) & ~63;
    for (int idx = t; idx < ne * NH; idx += 256) {
      const int el = idx >> 3;  // idx&7 == hw (8 | 256)
      const unsigned p = packed[e0 + el];
      const int j = p >> 16;
      const float av = __half2float(__ushort_as_half((unsigned short)(p & 0xffffu)));
      float lg = baseW + a_dst[j * NH + hw] + av * ewW;
      lg = (lg >= 0.f) ? lg : ALPHA * lg;
      const float wv = __expf(lg);
      wbuf[el][hw] = wv;
      sw += wv;
    }
    for (int el = ne + (t >> 3); el < nep; el += 32) wbuf[el][hw] = 0.f;
    __syncthreads();
    const int nb = nep >> 6;  // 64 edges per iteration; wave w takes el%4==w
    for (int b = 0; b < nb; ++b) {
      float4 f[BW];
#pragma unroll
      for (int q = 0; q < BW; ++q) {
        const int el = b * 64 + q * 4 + w;
        const int j = (int)(packed[e0 + el] >> 16);  // LDS broadcast
        f[q] = *(const float4*)(hfeat + (size_t)j * F + 4 * lane);
      }
#pragma unroll
      for (int q = 0; q < BW; ++q) {
        const int el = b * 64 + q * 4 + w;
        const float wv = wbuf[el][headF];
        acc4.x += wv * f[q].x;
        acc4.y += wv * f[q].y;
        acc4.z += wv * f[q].z;
        acc4.w += wv * f[q].w;
      }
    }
    __syncthreads();
  }

  // ---- cross-wave float4 partial + denominator reduction ----
  float* red = &wbuf[0][0];  // 4 KB of wbuf reused (post-barrier)
  *(float4*)(red + w * F + 4 * lane) = acc4;
  sred[t] = sw;
  __syncthreads();
  for (int off = 128; off >= NH; off >>= 1) {
    if (t < off) sred[t] += sred[t + off];
    __syncthreads();
  }
  const float s = sred[t >> 5];
  h_out[(size_t)i * F + t] =
      (red[t] + red[F + t] + red[2 * F + t] + red[3 * F + t]) / s;
}

// ---- Kernel D: y = h_out @ fuse_W^T + b, LayerNorm, ReLU ----
__global__ __launch_bounds__(256) void fuse_ln(const float* __restrict__ hin,
                                               const float* __restrict__ fW,
                                               const float* __restrict__ fb,
                                               const float* __restrict__ ln_g,
                                               const float* __restrict__ ln_b,
                                               float* __restrict__ out) {
  __shared__ float xs[8][F];
  __shared__ float ys[8][F];
  __shared__ float mu_s[8], rs_s[8];
  const int t = threadIdx.x;
  const int bi = blockIdx.x;
  for (int r = 0; r < 8; ++r) xs[r][t] = hin[(size_t)(bi * 8 + r) * F + t];
  __syncthreads();
  float acc[8];
#pragma unroll
  for (int r = 0; r < 8; ++r) acc[r] = 0.f;
  const float* wrow = fW + (size_t)t * F;
  for (int k = 0; k < F; k += 4) {
    const float4 w4 = *(const float4*)(wrow + k);
#pragma unroll
    for (int r = 0; r < 8; ++r) {
      const float4 xv = *(const float4*)(&xs[r][k]);
      acc[r] += w4.x * xv.x + w4.y * xv.y + w4.z * xv.z + w4.w * xv.w;
    }
  }
  const float fbt = fb[t];
  for (int r = 0; r < 8; ++r) ys[r][t] = acc[r] + fbt;
  __syncthreads();
  {
    const int r = t >> 5, c0 = t & 31;
    float sm = 0.f, sq = 0.f;
    for (int cc = c0; cc < F; cc += 32) {
      const float vv = ys[r][cc];
      sm += vv;
      sq += vv * vv;
    }
#pragma unroll
    for (int off = 1; off < 32; off <<= 1) {
      sm += __shfl_xor(sm, off);
      sq += __shfl_xor(sq, off);
    }
    if (c0 == 0) {
      const float mu = sm * (1.f / F);
      const float var = sq * (1.f / F) - mu * mu;
      mu_s[r] = mu;
      rs_s[r] = rsqrtf(var + LN_EPS);
    }
  }
  __syncthreads();
  const float g = ln_g[t], b = ln_b[t];
  for (int r = 0; r < 8; ++r) {
    const float vv = (ys[r][t] - mu_s[r]) * rs_s[r] * g + b;
    out[(size_t)(bi * 8 + r) * F + t] = fmaxf(vv, 0.f);
  }
}

extern "C" void kernel_launch(void* const* d_in, const int* in_sizes, int n_in,
                              void* d_out, int out_size, void* d_ws, size_t ws_size,
                              hipStream_t stream) {
  const float* x = (const float*)d_in[0];
  const float* adj = (const float*)d_in[1];
  const float* W = (const float*)d_in[2];
  const float* attn_src = (const float*)d_in[3];
  const float* attn_dst = (const float*)d_in[4];
  const float* edge_W = (const float*)d_in[5];
  const float* edge_b = (const float*)d_in[6];
  const float* fuse_W = (const float*)d_in[7];
  const float* fuse_b = (const float*)d_in[8];
  const float* ln_g = (const float*)d_in[9];
  const float* ln_b = (const float*)d_in[10];
  float* out = (float*)d_out;

  float* ws = (float*)d_ws;
  float* h = ws;                              // N*F
  float* a_src = h + (size_t)NN * F;          // N*8
  float* a_dst = a_src + (size_t)NN * NH;     // N*8
  float* h_out = a_dst + (size_t)NN * NH;     // N*F

  gemm_xwT<<<NN / 8, 256, 0, stream>>>(x, W, attn_src, attn_dst, h, a_src, a_dst);
  gat_attn<<<NN, 256, 0, stream>>>(adj, h, a_src, a_dst, edge_W, edge_b, h_out);
  fuse_ln<<<NN / 8, 256, 0, stream>>>(h_out, fuse_W, fuse_b, ln_g, ln_b, out);
}

// Round 7
// 91.563 us; speedup vs baseline: 1.9855x; 1.0825x over previous
//
#include <hip/hip_runtime.h>
#include <hip/hip_fp16.h>
#include <hip/hip_bf16.h>

#define NN 3072
#define F 256
#define NH 8
#define ALPHA 0.2f
#define LN_EPS 1e-5f
#define CH 384  // edge chunk (multiple of 64)
#define BW 16   // gathers in flight per thread

typedef float floatx4 __attribute__((ext_vector_type(4)));
typedef unsigned short ushortx4 __attribute__((ext_vector_type(4)));

// ---- Kernel A: h = x @ W^T (8 rows/block), bf16 h out + fused a_src/a_dst ----
__global__ __launch_bounds__(256) void gemm_xwT(const float* __restrict__ x,
                                                const float* __restrict__ W,
                                                const float* __restrict__ asrc_w,
                                                const float* __restrict__ adst_w,
                                                __hip_bfloat16* __restrict__ h,
                                                float* __restrict__ a_src,
                                                float* __restrict__ a_dst) {
  __shared__ float xs[8][F];
  const int t = threadIdx.x;
  const int bi = blockIdx.x;
  for (int r = 0; r < 8; ++r) xs[r][t] = x[(size_t)(bi * 8 + r) * F + t];
  __syncthreads();
  float acc[8];
#pragma unroll
  for (int r = 0; r < 8; ++r) acc[r] = 0.f;
  const float* wrow = W + (size_t)t * F;
  for (int k = 0; k < F; k += 4) {
    const float4 w4 = *(const float4*)(wrow + k);
#pragma unroll
    for (int r = 0; r < 8; ++r) {
      const float4 xv = *(const float4*)(&xs[r][k]);
      acc[r] += w4.x * xv.x + w4.y * xv.y + w4.z * xv.z + w4.w * xv.w;
    }
  }
  for (int r = 0; r < 8; ++r)
    h[(size_t)(bi * 8 + r) * F + t] = __float2bfloat16(acc[r]);
  // epilogue: per-head projections; col t weight = asrc_w[t]/adst_w[t]
  const float wsv = asrc_w[t];
  const float wdv = adst_w[t];
#pragma unroll
  for (int r = 0; r < 8; ++r) {
    float ps = acc[r] * wsv;
    float pd = acc[r] * wdv;
#pragma unroll
    for (int off = 1; off < 32; off <<= 1) {
      ps += __shfl_xor(ps, off);
      pd += __shfl_xor(pd, off);
    }
    if ((t & 31) == 0) {
      a_src[(size_t)(bi * 8 + r) * NH + (t >> 5)] = ps;
      a_dst[(size_t)(bi * 8 + r) * NH + (t >> 5)] = pd;
    }
  }
}

// ---- Kernel C: sparse masked multi-head attention, bf16 gathers ----
__global__ __launch_bounds__(256, 6) void gat_attn(const float* __restrict__ adj,
                                                   const __hip_bfloat16* __restrict__ hfeat,
                                                   const float* __restrict__ a_src,
                                                   const float* __restrict__ a_dst,
                                                   const float* __restrict__ edge_W,
                                                   const float* __restrict__ edge_b,
                                                   float* __restrict__ h_out) {
  __shared__ unsigned packed[NN + 64];  // (j<<16)|f16(av), 12.5 KB
  __shared__ float wbuf[CH][NH];        // 12 KB, conflict-free
  __shared__ float sred[256];
  __shared__ int wsum[4];
  const int t = threadIdx.x;
  const int i = blockIdx.x;
  const int w = t >> 6, lane = t & 63;
  const float* arow = adj + (size_t)i * NN;

  // ---- compaction: 12 entries/thread, wave-scan (2 barriers) ----
  const floatx4 r0 = __builtin_nontemporal_load((const floatx4*)(arow + t * 12));
  const floatx4 r1 = __builtin_nontemporal_load((const floatx4*)(arow + t * 12 + 4));
  const floatx4 r2 = __builtin_nontemporal_load((const floatx4*)(arow + t * 12 + 8));
  const float v[12] = {r0.x, r0.y, r0.z, r0.w, r1.x, r1.y, r1.z, r1.w,
                       r2.x, r2.y, r2.z, r2.w};
  int c = 0;
#pragma unroll
  for (int q = 0; q < 12; ++q) c += (v[q] > 0.f) ? 1 : 0;
  int xinc = c;  // wave inclusive scan
#pragma unroll
  for (int off = 1; off < 64; off <<= 1) {
    const int y = __shfl_up(xinc, off);
    if (lane >= off) xinc += y;
  }
  if (lane == 63) wsum[w] = xinc;
  __syncthreads();
  int cnt = 0, wpre = 0;
#pragma unroll
  for (int ww = 0; ww < 4; ++ww) {
    const int s = wsum[ww];
    if (ww < w) wpre += s;
    cnt += s;
  }
  int wofs = wpre + xinc - c;  // exclusive prefix
#pragma unroll
  for (int q = 0; q < 12; ++q) {
    if (v[q] > 0.f) {
      const unsigned j = (unsigned)(t * 12 + q);
      packed[wofs++] = (j << 16) | (unsigned)__half_as_ushort(__float2half(v[q]));
    }
  }
  if (t < 64) packed[cnt + t] = 0;  // pad: j=0, av=0 (weights forced 0)
  __syncthreads();

  // ---- chunked: weights (exp(l), shift-free softmax) + bf16 gathers ----
  const int hw = t & 7;
  const float baseW = a_src[i * NH + hw] + edge_b[hw];
  const float ewW = edge_W[hw];
  const int headF = lane >> 3;
  float sw = 0.f;
  float4 acc4 = {0.f, 0.f, 0.f, 0.f};
  for (int e0 = 0; e0 < cnt; e0 += CH) {
    const int ne = min(CH, cnt - e0);
    const int nep = (ne + 63) & ~63;
    for (int idx = t; idx < ne * NH; idx += 256) {
      const int el = idx >> 3;  // idx&7 == hw (8 | 256)
      const unsigned p = packed[e0 + el];
      const int j = p >> 16;
      const float av = __half2float(__ushort_as_half((unsigned short)(p & 0xffffu)));
      float lg = baseW + a_dst[j * NH + hw] + av * ewW;
      lg = (lg >= 0.f) ? lg : ALPHA * lg;
      const float wv = __expf(lg);
      wbuf[el][hw] = wv;
      sw += wv;
    }
    for (int el = ne + (t >> 3); el < nep; el += 32) wbuf[el][hw] = 0.f;
    __syncthreads();
    const int nb = nep >> 6;  // 64 edges per iteration; wave w takes el%4==w
    for (int b = 0; b < nb; ++b) {
      ushortx4 f[BW];
#pragma unroll
      for (int q = 0; q < BW; ++q) {
        const int el = b * 64 + q * 4 + w;
        const int j = (int)(packed[e0 + el] >> 16);  // LDS broadcast
        f[q] = *(const ushortx4*)(hfeat + (size_t)j * F + 4 * lane);
      }
#pragma unroll
      for (int q = 0; q < BW; ++q) {
        const int el = b * 64 + q * 4 + w;
        const float wv = wbuf[el][headF];
        acc4.x += wv * __uint_as_float((unsigned)f[q].x << 16);
        acc4.y += wv * __uint_as_float((unsigned)f[q].y << 16);
        acc4.z += wv * __uint_as_float((unsigned)f[q].z << 16);
        acc4.w += wv * __uint_as_float((unsigned)f[q].w << 16);
      }
    }
    __syncthreads();
  }

  // ---- cross-wave float4 partial + denominator reduction ----
  float* red = &wbuf[0][0];  // 4 KB of wbuf reused (post-barrier)
  *(float4*)(red + w * F + 4 * lane) = acc4;
  sred[t] = sw;
  __syncthreads();
  for (int off = 128; off >= NH; off >>= 1) {
    if (t < off) sred[t] += sred[t + off];
    __syncthreads();
  }
  const float s = sred[t >> 5];
  h_out[(size_t)i * F + t] =
      (red[t] + red[F + t] + red[2 * F + t] + red[3 * F + t]) / s;
}

// ---- Kernel D: y = h_out @ fuse_W^T + b, LayerNorm, ReLU ----
__global__ __launch_bounds__(256) void fuse_ln(const float* __restrict__ hin,
                                               const float* __restrict__ fW,
                                               const float* __restrict__ fb,
                                               const float* __restrict__ ln_g,
                                               const float* __restrict__ ln_b,
                                               float* __restrict__ out) {
  __shared__ float xs[8][F];
  __shared__ float ys[8][F];
  __shared__ float mu_s[8], rs_s[8];
  const int t = threadIdx.x;
  const int bi = blockIdx.x;
  for (int r = 0; r < 8; ++r) xs[r][t] = hin[(size_t)(bi * 8 + r) * F + t];
  __syncthreads();
  float acc[8];
#pragma unroll
  for (int r = 0; r < 8; ++r) acc[r] = 0.f;
  const float* wrow = fW + (size_t)t * F;
  for (int k = 0; k < F; k += 4) {
    const float4 w4 = *(const float4*)(wrow + k);
#pragma unroll
    for (int r = 0; r < 8; ++r) {
      const float4 xv = *(const float4*)(&xs[r][k]);
      acc[r] += w4.x * xv.x + w4.y * xv.y + w4.z * xv.z + w4.w * xv.w;
    }
  }
  const float fbt = fb[t];
  for (int r = 0; r < 8; ++r) ys[r][t] = acc[r] + fbt;
  __syncthreads();
  {
    const int r = t >> 5, c0 = t & 31;
    float sm = 0.f, sq = 0.f;
    for (int cc = c0; cc < F; cc += 32) {
      const float vv = ys[r][cc];
      sm += vv;
      sq += vv * vv;
    }
#pragma unroll
    for (int off = 1; off < 32; off <<= 1) {
      sm += __shfl_xor(sm, off);
      sq += __shfl_xor(sq, off);
    }
    if (c0 == 0) {
      const float mu = sm * (1.f / F);
      const float var = sq * (1.f / F) - mu * mu;
      mu_s[r] = mu;
      rs_s[r] = rsqrtf(var + LN_EPS);
    }
  }
  __syncthreads();
  const float g = ln_g[t], b = ln_b[t];
  for (int r = 0; r < 8; ++r) {
    const float vv = (ys[r][t] - mu_s[r]) * rs_s[r] * g + b;
    out[(size_t)(bi * 8 + r) * F + t] = fmaxf(vv, 0.f);
  }
}

extern "C" void kernel_launch(void* const* d_in, const int* in_sizes, int n_in,
                              void* d_out, int out_size, void* d_ws, size_t ws_size,
                              hipStream_t stream) {
  const float* x = (const float*)d_in[0];
  const float* adj = (const float*)d_in[1];
  const float* W = (const float*)d_in[2];
  const float* attn_src = (const float*)d_in[3];
  const float* attn_dst = (const float*)d_in[4];
  const float* edge_W = (const float*)d_in[5];
  const float* edge_b = (const float*)d_in[6];
  const float* fuse_W = (const float*)d_in[7];
  const float* fuse_b = (const float*)d_in[8];
  const float* ln_g = (const float*)d_in[9];
  const float* ln_b = (const float*)d_in[10];
  float* out = (float*)d_out;

  float* ws = (float*)d_ws;
  __hip_bfloat16* h = (__hip_bfloat16*)ws;            // N*F bf16 (= N*F/2 floats)
  float* a_src = ws + (size_t)NN * F / 2;             // N*8
  float* a_dst = a_src + (size_t)NN * NH;             // N*8
  float* h_out = a_dst + (size_t)NN * NH;             // N*F f32

  gemm_xwT<<<NN / 8, 256, 0, stream>>>(x, W, attn_src, attn_dst, h, a_src, a_dst);
  gat_attn<<<NN, 256, 0, stream>>>(adj, h, a_src, a_dst, edge_W, edge_b, h_out);
  fuse_ln<<<NN / 8, 256, 0, stream>>>(h_out, fuse_W, fuse_b, ln_g, ln_b, out);
}